// Round 1
// baseline (997.921 us; speedup 1.0000x reference)
//
#include <hip/hip_runtime.h>

#define SEQ   2048
#define HID   1024
#define NHEAD 16
#define DH    64
#define S2    1024   // 2*span
#define HG    8      // heads per band chunk

static __device__ __forceinline__ float4 ldsf4(const float* p) {
    return *reinterpret_cast<const float4*>(p);
}

// ---------------- QKV projection: qkv[n][o] = sum_k hidden[n][k]*W_in[o][k] ----------------
// scatter into per-head qT/kT/vT with bias + 1/sqrt(192) scaling on q
__global__ __launch_bounds__(256) void qkv_gemm_k(
    const float* __restrict__ hidden, const float* __restrict__ W_in,
    const float* __restrict__ q_bias, const float* __restrict__ v_bias,
    float* __restrict__ qT, float* __restrict__ kT, float* __restrict__ vT)
{
    __shared__ float As[16][68];
    __shared__ float Bs[16][68];
    const int tid = threadIdx.x;
    const int tx = tid & 15, ty = tid >> 4;
    const int n0 = blockIdx.y * 64, o0 = blockIdx.x * 64;
    float acc[4][4] = {};
    for (int k0 = 0; k0 < HID; k0 += 16) {
        __syncthreads();
        #pragma unroll
        for (int it = 0; it < 4; ++it) {
            int e = it * 256 + tid;
            int r = e >> 4, c = e & 15;
            As[c][r] = hidden[(n0 + r) * HID + (k0 + c)];
            Bs[c][r] = W_in[(o0 + r) * HID + (k0 + c)];
        }
        __syncthreads();
        #pragma unroll
        for (int kk = 0; kk < 16; ++kk) {
            float4 a = ldsf4(&As[kk][ty * 4]);
            float4 b = ldsf4(&Bs[kk][tx * 4]);
            float av[4] = {a.x, a.y, a.z, a.w};
            float bv[4] = {b.x, b.y, b.z, b.w};
            #pragma unroll
            for (int mi = 0; mi < 4; ++mi)
                #pragma unroll
                for (int ni = 0; ni < 4; ++ni)
                    acc[mi][ni] += av[mi] * bv[ni];
        }
    }
    const float inv_s = 0.07216878364870323f; // 1/sqrt(64*3)
    #pragma unroll
    for (int mi = 0; mi < 4; ++mi) {
        const int n = n0 + ty * 4 + mi;
        #pragma unroll
        for (int ni = 0; ni < 4; ++ni) {
            const int o = o0 + tx * 4 + ni;
            const int h = o / 192, c = o % 192;
            float v = acc[mi][ni];
            if (c < 64) {
                qT[(h * SEQ + n) * DH + c] = (v + q_bias[h * 64 + c]) * inv_s;
            } else if (c < 128) {
                kT[(h * SEQ + n) * DH + (c - 64)] = v;
            } else {
                vT[(h * SEQ + n) * DH + (c - 128)] = v + v_bias[h * 64 + (c - 128)];
            }
        }
    }
}

// ---------------- pos_k / pos_q GEMMs: M=1024(s) N=1024(o) K=1024 ----------------
__global__ __launch_bounds__(256) void pos_gemm_k(
    const float* __restrict__ rel, const float* __restrict__ W_pos,
    const float* __restrict__ W_posq, const float* __restrict__ b_posq,
    float* __restrict__ pos_k, float* __restrict__ pos_q)
{
    __shared__ float As[16][68];
    __shared__ float Bs[16][68];
    const int tid = threadIdx.x;
    const int tx = tid & 15, ty = tid >> 4;
    const int s0 = blockIdx.y * 64, o0 = blockIdx.x * 64;
    const int which = blockIdx.z;
    const float* __restrict__ W = which ? W_posq : W_pos;
    float acc[4][4] = {};
    for (int k0 = 0; k0 < HID; k0 += 16) {
        __syncthreads();
        #pragma unroll
        for (int it = 0; it < 4; ++it) {
            int e = it * 256 + tid;
            int r = e >> 4, c = e & 15;
            As[c][r] = rel[(s0 + r) * HID + (k0 + c)];
            Bs[c][r] = W[(o0 + r) * HID + (k0 + c)];
        }
        __syncthreads();
        #pragma unroll
        for (int kk = 0; kk < 16; ++kk) {
            float4 a = ldsf4(&As[kk][ty * 4]);
            float4 b = ldsf4(&Bs[kk][tx * 4]);
            float av[4] = {a.x, a.y, a.z, a.w};
            float bv[4] = {b.x, b.y, b.z, b.w};
            #pragma unroll
            for (int mi = 0; mi < 4; ++mi)
                #pragma unroll
                for (int ni = 0; ni < 4; ++ni)
                    acc[mi][ni] += av[mi] * bv[ni];
        }
    }
    const float inv_s = 0.07216878364870323f;
    #pragma unroll
    for (int mi = 0; mi < 4; ++mi) {
        const int s = s0 + ty * 4 + mi;
        #pragma unroll
        for (int ni = 0; ni < 4; ++ni) {
            const int o = o0 + tx * 4 + ni;
            const int h = o >> 6, c = o & 63;
            float v = acc[mi][ni];
            if (which) {
                pos_q[(h * S2 + s) * DH + c] = (v + b_posq[o]) * inv_s;
            } else {
                pos_k[(h * S2 + s) * DH + c] = v;
            }
        }
    }
}

// ---------------- band GEMM: out[hh][m][s] = dot(X[hh][m][:], P[hh][s][:]), K=64 ----------------
__global__ __launch_bounds__(256) void band_gemm_k(
    const float* __restrict__ X, const float* __restrict__ P, float* __restrict__ outb)
{
    __shared__ float Xs[64][68];
    __shared__ float Ps[64][68];
    const int tid = threadIdx.x;
    const int tx = tid & 15, ty = tid >> 4;
    const int hh = blockIdx.z;
    const int m0 = blockIdx.y * 64, s0 = blockIdx.x * 64;
    const float* __restrict__ Xh = X + (size_t)hh * SEQ * DH;
    const float* __restrict__ Ph = P + (size_t)hh * S2 * DH;
    #pragma unroll
    for (int it = 0; it < 16; ++it) {
        int e = it * 256 + tid;
        int r = e >> 6, c = e & 63;
        Xs[c][r] = Xh[(m0 + r) * DH + c];
        Ps[c][r] = Ph[(s0 + r) * DH + c];
    }
    __syncthreads();
    float acc[4][4] = {};
    #pragma unroll 8
    for (int c = 0; c < 64; ++c) {
        float4 a = ldsf4(&Xs[c][ty * 4]);
        float4 b = ldsf4(&Ps[c][tx * 4]);
        float av[4] = {a.x, a.y, a.z, a.w};
        float bv[4] = {b.x, b.y, b.z, b.w};
        #pragma unroll
        for (int mi = 0; mi < 4; ++mi)
            #pragma unroll
            for (int ni = 0; ni < 4; ++ni)
                acc[mi][ni] += av[mi] * bv[ni];
    }
    #pragma unroll
    for (int mi = 0; mi < 4; ++mi) {
        const int m = m0 + ty * 4 + mi;
        float4 st = make_float4(acc[mi][0], acc[mi][1], acc[mi][2], acc[mi][3]);
        *reinterpret_cast<float4*>(&outb[((size_t)hh * SEQ + m) * S2 + s0 + tx * 4]) = st;
    }
}

// ---------------- flash attention with gathered rel-pos bias ----------------
__global__ __launch_bounds__(256) void attn_k(
    int h0,
    const float* __restrict__ qT, const float* __restrict__ kT, const float* __restrict__ vT,
    const float* __restrict__ c2p, const float* __restrict__ p2c,
    const int* __restrict__ amask, float* __restrict__ out)
{
    __shared__ float Qs[64][68];
    __shared__ float Ks[64][68];
    __shared__ float Vs[64][68];
    __shared__ float Ss[64][72];
    const int tid = threadIdx.x;
    const int tx = tid & 15, ty = tid >> 4;
    const int hh = blockIdx.y, h = h0 + hh;
    const int i0 = blockIdx.x * 64;
    const float* __restrict__ qh = qT + (size_t)h * SEQ * DH;
    const float* __restrict__ kh = kT + (size_t)h * SEQ * DH;
    const float* __restrict__ vh = vT + (size_t)h * SEQ * DH;
    const float* __restrict__ c2ph = c2p + (size_t)hh * SEQ * S2;
    const float* __restrict__ p2ch = p2c + (size_t)hh * SEQ * S2;

    #pragma unroll
    for (int it = 0; it < 16; ++it) {
        int e = it * 256 + tid;
        int r = e >> 6, c = e & 63;
        Qs[c][r] = qh[(i0 + r) * DH + c];
    }

    float O[4][4] = {};
    float mrow[4], lrow[4];
    #pragma unroll
    for (int mi = 0; mi < 4; ++mi) { mrow[mi] = -1.0e30f; lrow[mi] = 0.f; }

    for (int j0 = 0; j0 < SEQ; j0 += 64) {
        __syncthreads();
        #pragma unroll
        for (int it = 0; it < 16; ++it) {
            int e = it * 256 + tid;
            int r = e >> 6, c = e & 63;
            Ks[c][r] = kh[(j0 + r) * DH + c];
            Vs[r][c] = vh[(j0 + r) * DH + c];
        }
        __syncthreads();

        // S = q k^T
        float sacc[4][4] = {};
        #pragma unroll 8
        for (int c = 0; c < 64; ++c) {
            float4 a = ldsf4(&Qs[c][ty * 4]);
            float4 b = ldsf4(&Ks[c][tx * 4]);
            float av[4] = {a.x, a.y, a.z, a.w};
            float bv[4] = {b.x, b.y, b.z, b.w};
            #pragma unroll
            for (int mi = 0; mi < 4; ++mi)
                #pragma unroll
                for (int ni = 0; ni < 4; ++ni)
                    sacc[mi][ni] += av[mi] * bv[ni];
        }
        // rel-pos bias gather + mask
        #pragma unroll
        for (int mi = 0; mi < 4; ++mi) {
            const int i = i0 + ty * 4 + mi;
            #pragma unroll
            for (int ni = 0; ni < 4; ++ni) {
                const int j = j0 + tx * 4 + ni;
                int s = i - j + 512;
                s = s < 0 ? 0 : (s > 1023 ? 1023 : s);
                float v = sacc[mi][ni] + c2ph[(size_t)i * S2 + s] + p2ch[(size_t)j * S2 + s];
                sacc[mi][ni] = amask[(size_t)i * SEQ + j] ? v : -1.0e30f;
            }
        }
        // online softmax (rows owned by 16 tx-lanes, contiguous within a wave)
        #pragma unroll
        for (int mi = 0; mi < 4; ++mi) {
            float m4 = fmaxf(fmaxf(sacc[mi][0], sacc[mi][1]), fmaxf(sacc[mi][2], sacc[mi][3]));
            #pragma unroll
            for (int off = 1; off < 16; off <<= 1)
                m4 = fmaxf(m4, __shfl_xor(m4, off, 64));
            float newM = fmaxf(mrow[mi], m4);
            bool live = newM > -5.0e29f;
            float scale = live ? __expf(mrow[mi] - newM) : 1.0f;
            float psum = 0.f;
            #pragma unroll
            for (int ni = 0; ni < 4; ++ni) {
                float p = live ? __expf(sacc[mi][ni] - newM) : 0.f;
                sacc[mi][ni] = p;
                psum += p;
            }
            #pragma unroll
            for (int off = 1; off < 16; off <<= 1)
                psum += __shfl_xor(psum, off, 64);
            lrow[mi] = lrow[mi] * scale + psum;
            mrow[mi] = newM;
            #pragma unroll
            for (int ni = 0; ni < 4; ++ni) O[mi][ni] *= scale;
        }
        // write P
        #pragma unroll
        for (int mi = 0; mi < 4; ++mi) {
            float4 st = make_float4(sacc[mi][0], sacc[mi][1], sacc[mi][2], sacc[mi][3]);
            *reinterpret_cast<float4*>(&Ss[ty * 4 + mi][tx * 4]) = st;
        }
        __syncthreads();
        // O += P V
        #pragma unroll 4
        for (int jv = 0; jv < 16; ++jv) {
            float4 vv[4];
            #pragma unroll
            for (int e = 0; e < 4; ++e) vv[e] = ldsf4(&Vs[jv * 4 + e][tx * 4]);
            #pragma unroll
            for (int mi = 0; mi < 4; ++mi) {
                float4 p4 = ldsf4(&Ss[ty * 4 + mi][jv * 4]);
                O[mi][0] += p4.x * vv[0].x + p4.y * vv[1].x + p4.z * vv[2].x + p4.w * vv[3].x;
                O[mi][1] += p4.x * vv[0].y + p4.y * vv[1].y + p4.z * vv[2].y + p4.w * vv[3].y;
                O[mi][2] += p4.x * vv[0].z + p4.y * vv[1].z + p4.z * vv[2].z + p4.w * vv[3].z;
                O[mi][3] += p4.x * vv[0].w + p4.y * vv[1].w + p4.z * vv[2].w + p4.w * vv[3].w;
            }
        }
    }

    #pragma unroll
    for (int mi = 0; mi < 4; ++mi) {
        const int n = i0 + ty * 4 + mi;
        bool live = (mrow[mi] > -5.0e29f) && (lrow[mi] > 0.f);
        float rinv = live ? 1.0f / lrow[mi] : 0.f;
        float4 o4 = make_float4(O[mi][0] * rinv, O[mi][1] * rinv, O[mi][2] * rinv, O[mi][3] * rinv);
        *reinterpret_cast<float4*>(&out[(size_t)n * HID + h * 64 + tx * 4]) = o4;
    }
}

extern "C" void kernel_launch(void* const* d_in, const int* in_sizes, int n_in,
                              void* d_out, int out_size, void* d_ws, size_t ws_size,
                              hipStream_t stream)
{
    const float* hidden  = (const float*)d_in[0];
    const int*   amask   = (const int*)  d_in[1];
    const float* W_in    = (const float*)d_in[2];
    const float* q_bias  = (const float*)d_in[3];
    const float* v_bias  = (const float*)d_in[4];
    const float* W_pos   = (const float*)d_in[5];
    const float* W_posq  = (const float*)d_in[6];
    const float* b_posq  = (const float*)d_in[7];
    const float* rel_emb = (const float*)d_in[8];
    float* out = (float*)d_out;

    float* ws    = (float*)d_ws;
    float* qT    = ws;                    // 16*2048*64 = 2M floats
    float* kT    = qT + 2097152;
    float* vT    = kT + 2097152;
    float* pos_k = vT + 2097152;          // 16*1024*64 = 1M floats
    float* pos_q = pos_k + 1048576;
    float* c2p   = pos_q + 1048576;       // 8*2048*1024 = 16M floats
    float* p2c   = c2p + 16777216;        // 16M floats
    // total 40M floats = 160 MB

    qkv_gemm_k<<<dim3(48, 32), 256, 0, stream>>>(hidden, W_in, q_bias, v_bias, qT, kT, vT);
    pos_gemm_k<<<dim3(16, 16, 2), 256, 0, stream>>>(rel_emb, W_pos, W_posq, b_posq, pos_k, pos_q);
    for (int h0 = 0; h0 < NHEAD; h0 += HG) {
        band_gemm_k<<<dim3(16, 32, HG), 256, 0, stream>>>(qT + (size_t)h0 * SEQ * DH, pos_k + (size_t)h0 * S2 * DH, c2p);
        band_gemm_k<<<dim3(16, 32, HG), 256, 0, stream>>>(kT + (size_t)h0 * SEQ * DH, pos_q + (size_t)h0 * S2 * DH, p2c);
        attn_k<<<dim3(32, HG), 256, 0, stream>>>(h0, qT, kT, vT, c2p, p2c, amask, out);
    }
}

// Round 2
// 264.431 us; speedup vs baseline: 3.7738x; 3.7738x over previous
//
#include <hip/hip_runtime.h>

#define SEQ   2048
#define HID   1024
#define NHEAD 16
#define DH    64
#define S2    1024

typedef short bf16x8 __attribute__((ext_vector_type(8)));
typedef float f32x4  __attribute__((ext_vector_type(4)));

static __device__ __forceinline__ short f2bf(float f) {
    unsigned u = __float_as_uint(f);
    unsigned r = (u + 0x7fffu + ((u >> 16) & 1u)) >> 16;
    return (short)r;
}
static __device__ __forceinline__ float bf2f(short h) {
    return __uint_as_float(((unsigned)(unsigned short)h) << 16);
}

// ---------------- fp32 -> bf16 conversion ----------------
__global__ __launch_bounds__(256) void cvt_bf16_k(const float* __restrict__ in,
                                                  short* __restrict__ out, int n8) {
    int idx = blockIdx.x * 256 + threadIdx.x;
    if (idx < n8) {
        const float4 a = ((const float4*)in)[idx * 2];
        const float4 b = ((const float4*)in)[idx * 2 + 1];
        bf16x8 r;
        r[0] = f2bf(a.x); r[1] = f2bf(a.y); r[2] = f2bf(a.z); r[3] = f2bf(a.w);
        r[4] = f2bf(b.x); r[5] = f2bf(b.y); r[6] = f2bf(b.z); r[7] = f2bf(b.w);
        ((bf16x8*)out)[idx] = r;
    }
}

// ---------------- shared MFMA GEMM core: C[128x64] += A[128xK] * B[64xK]^T ----------------
// A, B row-major bf16, K-contiguous. LDS tiles XOR-swizzled in 16B chunks.
static __device__ __forceinline__ void gemm_tile(
    const short* __restrict__ Ag, int lda,
    const short* __restrict__ Bg, int ldb,
    int K, short* As, short* Bs, f32x4 (&acc)[4][2])
{
    const int tid = threadIdx.x;
    const int lane = tid & 63, w = tid >> 6;
    const int g = lane >> 4, ln = lane & 15;
    const int wm = (w >> 1) * 64, wn = (w & 1) * 32;
    for (int kt = 0; kt < K; kt += 64) {
        __syncthreads();
        #pragma unroll
        for (int it = 0; it < 4; ++it) {
            int c = it * 256 + tid;
            int r = c >> 3, cb = c & 7;
            uint4 v = *(const uint4*)(Ag + (size_t)r * lda + kt + ((cb ^ (r & 7)) << 3));
            *(uint4*)(As + r * 64 + cb * 8) = v;
        }
        #pragma unroll
        for (int it = 0; it < 2; ++it) {
            int c = it * 256 + tid;
            int r = c >> 3, cb = c & 7;
            uint4 v = *(const uint4*)(Bg + (size_t)r * ldb + kt + ((cb ^ (r & 7)) << 3));
            *(uint4*)(Bs + r * 64 + cb * 8) = v;
        }
        __syncthreads();
        #pragma unroll
        for (int k0 = 0; k0 < 2; ++k0) {
            bf16x8 bfr[2];
            #pragma unroll
            for (int nf = 0; nf < 2; ++nf) {
                int rr = wn + nf * 16 + ln;
                int kc = (k0 * 4 + g) ^ (rr & 7);
                bfr[nf] = *(const bf16x8*)(Bs + rr * 64 + kc * 8);
            }
            #pragma unroll
            for (int mf = 0; mf < 4; ++mf) {
                int rr = wm + mf * 16 + ln;
                int kc = (k0 * 4 + g) ^ (rr & 7);
                bf16x8 afr = *(const bf16x8*)(As + rr * 64 + kc * 8);
                #pragma unroll
                for (int nf = 0; nf < 2; ++nf)
                    acc[mf][nf] = __builtin_amdgcn_mfma_f32_16x16x32_bf16(afr, bfr[nf], acc[mf][nf], 0, 0, 0);
            }
        }
    }
}

// ---------------- QKV projection ----------------
__global__ __launch_bounds__(256) void qkv_mfma_k(
    const short* __restrict__ hid, const short* __restrict__ win,
    const float* __restrict__ q_bias, const float* __restrict__ v_bias,
    short* __restrict__ qT, short* __restrict__ kT, short* __restrict__ vT)
{
    __shared__ __align__(16) short As[128 * 64];
    __shared__ __align__(16) short Bs[64 * 64];
    const int tid = threadIdx.x, lane = tid & 63, w = tid >> 6;
    const int g = lane >> 4, ln = lane & 15;
    const int wm = (w >> 1) * 64, wn = (w & 1) * 32;
    const int m0 = blockIdx.y * 128, n0 = blockIdx.x * 64;
    f32x4 acc[4][2] = {};
    gemm_tile(hid + (size_t)m0 * HID, HID, win + (size_t)n0 * HID, HID, HID, As, Bs, acc);
    const float inv_s = 0.07216878364870323f;
    #pragma unroll
    for (int mf = 0; mf < 4; ++mf) {
        #pragma unroll
        for (int nf = 0; nf < 2; ++nf) {
            #pragma unroll
            for (int reg = 0; reg < 4; ++reg) {
                int m = m0 + wm + mf * 16 + 4 * g + reg;
                int n = n0 + wn + nf * 16 + ln;
                int h = n / 192, c = n % 192;
                float v = acc[mf][nf][reg];
                if (c < 64)       qT[((size_t)h * SEQ + m) * DH + c]        = f2bf((v + q_bias[h * 64 + c]) * inv_s);
                else if (c < 128) kT[((size_t)h * SEQ + m) * DH + (c - 64)] = f2bf(v);
                else              vT[((size_t)h * SEQ + m) * DH + (c - 128)] = f2bf(v + v_bias[h * 64 + (c - 128)]);
            }
        }
    }
}

// ---------------- pos_k / pos_q ----------------
__global__ __launch_bounds__(256) void pos_mfma_k(
    const short* __restrict__ rel, const short* __restrict__ wpos, const short* __restrict__ wposq,
    const float* __restrict__ b_posq, short* __restrict__ posk, short* __restrict__ posq)
{
    __shared__ __align__(16) short As[128 * 64];
    __shared__ __align__(16) short Bs[64 * 64];
    const int tid = threadIdx.x, lane = tid & 63, w = tid >> 6;
    const int g = lane >> 4, ln = lane & 15;
    const int wm = (w >> 1) * 64, wn = (w & 1) * 32;
    const int m0 = blockIdx.y * 128, n0 = blockIdx.x * 64;
    const int which = blockIdx.z;
    const short* Bg = (which ? wposq : wpos) + (size_t)n0 * HID;
    f32x4 acc[4][2] = {};
    gemm_tile(rel + (size_t)m0 * HID, HID, Bg, HID, HID, As, Bs, acc);
    const float inv_s = 0.07216878364870323f;
    #pragma unroll
    for (int mf = 0; mf < 4; ++mf) {
        #pragma unroll
        for (int nf = 0; nf < 2; ++nf) {
            #pragma unroll
            for (int reg = 0; reg < 4; ++reg) {
                int s = m0 + wm + mf * 16 + 4 * g + reg;
                int o = n0 + wn + nf * 16 + ln;
                int h = o >> 6, c = o & 63;
                float v = acc[mf][nf][reg];
                if (which) posq[((size_t)h * S2 + s) * DH + c] = f2bf((v + b_posq[o]) * inv_s);
                else       posk[((size_t)h * S2 + s) * DH + c] = f2bf(v);
            }
        }
    }
}

// ---------------- band GEMMs (c2p / p2c), K=64 ----------------
__global__ __launch_bounds__(256) void band_mfma_k(
    const short* __restrict__ qT, const short* __restrict__ kT,
    const short* __restrict__ posk, const short* __restrict__ posq,
    short* __restrict__ c2p, short* __restrict__ p2c)
{
    __shared__ __align__(16) short As[128 * 64];
    __shared__ __align__(16) short Bs[64 * 64];
    const int tid = threadIdx.x, lane = tid & 63, w = tid >> 6;
    const int g = lane >> 4, ln = lane & 15;
    const int wm = (w >> 1) * 64, wn = (w & 1) * 32;
    const int m0 = blockIdx.y * 128, n0 = blockIdx.x * 64;
    const int head = blockIdx.z >> 1, which = blockIdx.z & 1;
    const short* Ag = (which ? kT : qT) + (size_t)head * SEQ * DH + (size_t)m0 * DH;
    const short* Bg = (which ? posq : posk) + (size_t)head * S2 * DH + (size_t)n0 * DH;
    short* outb = (which ? p2c : c2p) + (size_t)head * SEQ * S2;
    f32x4 acc[4][2] = {};
    gemm_tile(Ag, DH, Bg, DH, 64, As, Bs, acc);
    #pragma unroll
    for (int mf = 0; mf < 4; ++mf) {
        #pragma unroll
        for (int nf = 0; nf < 2; ++nf) {
            #pragma unroll
            for (int reg = 0; reg < 4; ++reg) {
                int m = m0 + wm + mf * 16 + 4 * g + reg;
                int n = n0 + wn + nf * 16 + ln;
                outb[(size_t)m * S2 + n] = f2bf(acc[mf][nf][reg]);
            }
        }
    }
}

// ---------------- V transpose per head: vT[h][n][d] -> vTt[h][d][n] ----------------
__global__ __launch_bounds__(256) void vtrans_k(const short* __restrict__ vT, short* __restrict__ vTt)
{
    __shared__ short T[64][72];
    const int h = blockIdx.y, n0 = blockIdx.x * 64;
    const int tid = threadIdx.x;
    const int r = tid >> 3, cb = tid & 7;
    #pragma unroll
    for (int it = 0; it < 2; ++it) {
        int row = it * 32 + r;
        *(uint4*)(&T[row][cb * 8]) = *(const uint4*)(vT + ((size_t)h * SEQ + n0 + row) * DH + cb * 8);
    }
    __syncthreads();
    #pragma unroll
    for (int it = 0; it < 2; ++it) {
        int d = it * 32 + r;
        short tmp[8];
        #pragma unroll
        for (int e = 0; e < 8; ++e) tmp[e] = T[cb * 8 + e][d];
        *(uint4*)(vTt + ((size_t)h * DH + d) * SEQ + n0 + cb * 8) = *(uint4*)tmp;
    }
}

// ---------------- MFMA flash attention ----------------
__global__ __launch_bounds__(256) void attn_mfma_k(
    const short* __restrict__ qT, const short* __restrict__ kT, const short* __restrict__ vTt,
    const short* __restrict__ c2p, const short* __restrict__ p2c,
    const int* __restrict__ amask, float* __restrict__ out)
{
    __shared__ __align__(16) short Ks[64 * 64];
    __shared__ __align__(16) short Vs[64 * 64];
    __shared__ __align__(16) short Ps[4][16 * 72];
    const int tid = threadIdx.x, lane = tid & 63, w = tid >> 6;
    const int g = lane >> 4, ln = lane & 15;
    const int h = blockIdx.y, i0 = blockIdx.x * 64;
    const int iw = i0 + w * 16;
    const short* qh = qT + (size_t)h * SEQ * DH;
    const short* kh = kT + (size_t)h * SEQ * DH;
    const short* vh = vTt + (size_t)h * DH * SEQ;
    const short* ch = c2p + (size_t)h * SEQ * S2;
    const short* ph = p2c + (size_t)h * SEQ * S2;

    bf16x8 aq[2];
    aq[0] = *(const bf16x8*)(qh + (size_t)(iw + ln) * DH + 0  + g * 8);
    aq[1] = *(const bf16x8*)(qh + (size_t)(iw + ln) * DH + 32 + g * 8);

    f32x4 o4[4] = {};
    float mrow[4], lrow[4];
    #pragma unroll
    for (int reg = 0; reg < 4; ++reg) { mrow[reg] = -1.0e30f; lrow[reg] = 0.f; }

    for (int jt = 0; jt < 32; ++jt) {
        const int j0 = jt * 64;
        __syncthreads();
        #pragma unroll
        for (int it = 0; it < 2; ++it) {
            int c = it * 256 + tid;
            int r = c >> 3, cb = c & 7;
            *(uint4*)(Ks + r * 64 + cb * 8) = *(const uint4*)(kh + (size_t)(j0 + r) * DH + ((cb ^ (r & 7)) << 3));
            *(uint4*)(Vs + r * 64 + cb * 8) = *(const uint4*)(vh + (size_t)r * SEQ + j0 + ((cb ^ (r & 7)) << 3));
        }
        __syncthreads();

        // S = Q K^T  (D rows = i-local, cols = j-local)
        f32x4 sfr[4];
        #pragma unroll
        for (int nf = 0; nf < 4; ++nf) sfr[nf] = (f32x4){0.f, 0.f, 0.f, 0.f};
        #pragma unroll
        for (int k0 = 0; k0 < 2; ++k0) {
            #pragma unroll
            for (int nf = 0; nf < 4; ++nf) {
                int rr = nf * 16 + ln;
                bf16x8 bk = *(const bf16x8*)(Ks + rr * 64 + (((k0 * 4 + g) ^ (rr & 7)) << 3));
                sfr[nf] = __builtin_amdgcn_mfma_f32_16x16x32_bf16(aq[k0], bk, sfr[nf], 0, 0, 0);
            }
        }

        // bias gather + mask
        float p[4][4];
        #pragma unroll
        for (int reg = 0; reg < 4; ++reg) {
            int i = iw + 4 * g + reg;
            #pragma unroll
            for (int nf = 0; nf < 4; ++nf) {
                int j = j0 + nf * 16 + ln;
                int s = i - j + 512; s = s < 0 ? 0 : (s > 1023 ? 1023 : s);
                float sc = sfr[nf][reg] + bf2f(ch[(size_t)i * S2 + s]) + bf2f(ph[(size_t)j * S2 + s]);
                p[reg][nf] = amask[(size_t)i * SEQ + j] ? sc : -1.0e30f;
            }
        }

        // online softmax per row (row = 4g+reg, j spread over 16 lanes x 4 nf)
        float scl[4];
        #pragma unroll
        for (int reg = 0; reg < 4; ++reg) {
            float mx = fmaxf(fmaxf(p[reg][0], p[reg][1]), fmaxf(p[reg][2], p[reg][3]));
            #pragma unroll
            for (int off = 1; off < 16; off <<= 1) mx = fmaxf(mx, __shfl_xor(mx, off, 64));
            float nm = fmaxf(mrow[reg], mx);
            bool live = nm > -5.0e29f;
            float sc = live ? __expf(mrow[reg] - nm) : 1.f;
            float rs = 0.f;
            #pragma unroll
            for (int nf = 0; nf < 4; ++nf) {
                float e = live ? __expf(p[reg][nf] - nm) : 0.f;
                p[reg][nf] = e; rs += e;
            }
            #pragma unroll
            for (int off = 1; off < 16; off <<= 1) rs += __shfl_xor(rs, off, 64);
            lrow[reg] = lrow[reg] * sc + rs;
            mrow[reg] = nm;
            scl[reg] = sc;
        }

        // write P (row-major [i-local][j-local]) for PV B-frags
        #pragma unroll
        for (int reg = 0; reg < 4; ++reg)
            #pragma unroll
            for (int nf = 0; nf < 4; ++nf)
                Ps[w][(4 * g + reg) * 72 + nf * 16 + ln] = f2bf(p[reg][nf]);

        // rescale O (O^T layout: lane owns col i = ln) with redistributed scale
        {
            int srcl = ((ln >> 2) << 4) + ln;
            float s0 = __shfl(scl[0], srcl, 64), s1 = __shfl(scl[1], srcl, 64);
            float s2 = __shfl(scl[2], srcl, 64), s3 = __shfl(scl[3], srcl, 64);
            int rsel = ln & 3;
            float sc = rsel == 0 ? s0 : (rsel == 1 ? s1 : (rsel == 2 ? s2 : s3));
            #pragma unroll
            for (int mf = 0; mf < 4; ++mf)
                #pragma unroll
                for (int reg = 0; reg < 4; ++reg) o4[mf][reg] *= sc;
        }

        // O^T += V^T * P^T : A = Vt rows d, B = P^T (k=j, n=i)
        #pragma unroll
        for (int k0 = 0; k0 < 2; ++k0) {
            bf16x8 bp = *(const bf16x8*)(&Ps[w][ln * 72 + k0 * 32 + g * 8]);
            #pragma unroll
            for (int mf = 0; mf < 4; ++mf) {
                int rr = mf * 16 + ln;
                bf16x8 av = *(const bf16x8*)(Vs + rr * 64 + (((k0 * 4 + g) ^ (rr & 7)) << 3));
                o4[mf] = __builtin_amdgcn_mfma_f32_16x16x32_bf16(av, bp, o4[mf], 0, 0, 0);
            }
        }
    }

    // redistribute 1/l to O^T lanes and store
    float lo[4];
    #pragma unroll
    for (int reg = 0; reg < 4; ++reg)
        lo[reg] = (mrow[reg] > -5.0e29f && lrow[reg] > 0.f) ? 1.f / lrow[reg] : 0.f;
    int srcl = ((ln >> 2) << 4) + ln;
    float l0 = __shfl(lo[0], srcl, 64), l1 = __shfl(lo[1], srcl, 64);
    float l2 = __shfl(lo[2], srcl, 64), l3 = __shfl(lo[3], srcl, 64);
    int rsel = ln & 3;
    float linv = rsel == 0 ? l0 : (rsel == 1 ? l1 : (rsel == 2 ? l2 : l3));
    #pragma unroll
    for (int mf = 0; mf < 4; ++mf)
        #pragma unroll
        for (int reg = 0; reg < 4; ++reg) {
            int d = mf * 16 + 4 * g + reg;
            out[(size_t)(i0 + w * 16 + ln) * HID + h * 64 + d] = o4[mf][reg] * linv;
        }
}

extern "C" void kernel_launch(void* const* d_in, const int* in_sizes, int n_in,
                              void* d_out, int out_size, void* d_ws, size_t ws_size,
                              hipStream_t stream)
{
    const float* hidden  = (const float*)d_in[0];
    const int*   amask   = (const int*)  d_in[1];
    const float* W_in    = (const float*)d_in[2];
    const float* q_bias  = (const float*)d_in[3];
    const float* v_bias  = (const float*)d_in[4];
    const float* W_pos   = (const float*)d_in[5];
    const float* W_posq  = (const float*)d_in[6];
    const float* b_posq  = (const float*)d_in[7];
    const float* rel_emb = (const float*)d_in[8];
    float* out = (float*)d_out;

    short* ws = (short*)d_ws;
    short* hid_bf   = ws;                      // 2,097,152 (aliased by vTt later)
    short* win_bf   = ws + 2097152;            // 3,145,728
    short* rel_bf   = ws + 5242880;            // 1,048,576
    short* wpos_bf  = ws + 6291456;            // 1,048,576
    short* wposq_bf = ws + 7340032;            // 1,048,576
    short* qT       = ws + 8388608;            // 2,097,152
    short* kT       = ws + 10485760;           // 2,097,152
    short* vT       = ws + 12582912;           // 2,097,152
    short* posk     = ws + 14680064;           // 1,048,576
    short* posq     = ws + 15728640;           // 1,048,576
    short* c2p      = ws + 16777216;           // 33,554,432
    short* p2c      = ws + 50331648;           // 33,554,432
    short* vTt      = hid_bf;                  // reuse (hid dead after qkv)

    cvt_bf16_k<<<2097152 / 8 / 256, 256, 0, stream>>>(hidden, hid_bf, 2097152 / 8);
    cvt_bf16_k<<<3145728 / 8 / 256, 256, 0, stream>>>(W_in, win_bf, 3145728 / 8);
    cvt_bf16_k<<<1048576 / 8 / 256, 256, 0, stream>>>(rel_emb, rel_bf, 1048576 / 8);
    cvt_bf16_k<<<1048576 / 8 / 256, 256, 0, stream>>>(W_pos, wpos_bf, 1048576 / 8);
    cvt_bf16_k<<<1048576 / 8 / 256, 256, 0, stream>>>(W_posq, wposq_bf, 1048576 / 8);

    qkv_mfma_k<<<dim3(48, 16), 256, 0, stream>>>(hid_bf, win_bf, q_bias, v_bias, qT, kT, vT);
    vtrans_k<<<dim3(32, 16), 256, 0, stream>>>(vT, vTt);
    pos_mfma_k<<<dim3(16, 8, 2), 256, 0, stream>>>(rel_bf, wpos_bf, wposq_bf, b_posq, posk, posq);
    band_mfma_k<<<dim3(16, 16, 32), 256, 0, stream>>>(qT, kT, posk, posq, c2p, p2c);
    attn_mfma_k<<<dim3(32, 16), 256, 0, stream>>>(qT, kT, vTt, c2p, p2c, amask, out);
}